// Round 6
// baseline (1879.806 us; speedup 1.0000x reference)
//
#include <hip/hip_runtime.h>

// CANPathIntegrator — MI355X round 6: 4-block row-split groups, all 256 CUs.
// 64 groups x 8 batches; group g = blocks {g, g+64, g+128, g+192} (same XCD
// under bid%8 round-robin — perf heuristic only). Block s of a group computes
// w rows [128s,128s+128) (A-slice 256 KB/step, col-coalesced via A=A^T).
// Per-step cross-block coupling = 16 floats (sum_k g_k*omega_k partials),
// exchanged via tagged double-buffered mailbox in d_ws (agent-scope
// release/acquire). All 256 blocks co-resident (1 block/CU by LDS) -> spin
// is safe; SPIN_CAP guarantees termination. Pure f32 math (= R2/R5 numerics).

namespace {
constexpr int NT = 128;
constexpr int ND = 512;
constexpr int NBATCH = 8;
constexpr int NGROUP = 64;
constexpr int SPIN_CAP = 1 << 24;
}

struct Shm {
    float4 zxv[ND][2];        // zx[j][batch0..7] as 2 float4        16 KB
    float  wpE[16][64][12];   // [jg][cp][b] even-col partials       48 KB
    float  wpO[16][64][12];   // odd-col partials                    48 KB
    float2 gpart[8][8];       // [wave][b] (d0,d1) partials
    float  dxpart[16];        // this block's partial, idx = 2b+c
    float  dxs[16];           // group-total dx_can sums
    float2 dpi[NBATCH][NT];   // dx_pi preload                        8 KB
    float2 om[256];           // omega pairs                          2 KB
};

__global__ __launch_bounds__(1024) void can_main(
    const float* __restrict__ dx_pi, const float* __restrict__ z0,
    const float* __restrict__ x0, const float* __restrict__ omega,
    const float* __restrict__ A, const float* __restrict__ z0b,
    float* __restrict__ d_out, unsigned int* __restrict__ ws)
{
    __shared__ Shm sh;
    const int tid = threadIdx.x;
    const int g   = blockIdx.x & 63;   // batch group
    const int s   = blockIdx.x >> 6;   // row-split slot 0..3
    const int b0  = g * NBATCH;

    float* z_seq = d_out;
    float* x_seq = d_out + (size_t)512 * NT * ND;

    unsigned int* flags = ws;          // [64][2][4]
    unsigned int* pay   = ws + 512;    // [64][2][4][16]

    // ---- preload dx_pi (8 batches) and omega ----
    {
        int b = tid >> 7, tt = tid & 127;
        sh.dpi[b][tt] =
            reinterpret_cast<const float2*>(dx_pi)[(size_t)(b0 + b) * NT + tt];
    }
    if (tid < 256)
        sh.om[tid] = reinterpret_cast<const float2*>(omega)[tid];

    // ---- ||z0_base|| (reuse dxpart as scratch) ----
    float sq = 0.f;
    if (tid < ND) { float f = z0b[tid]; sq = f * f; }
    #pragma unroll
    for (int o = 1; o < 64; o <<= 1) sq += __shfl_xor(sq, o, 64);
    if ((tid & 63) == 0) sh.dxpart[tid >> 6] = sq;
    __syncthreads();
    float nsq = 0.f;
    #pragma unroll
    for (int w = 0; w < 16; ++w) nsq += sh.dxpart[w];
    const float zinv = 1.0f / (sqrtf(nsq) + 1e-5f);

    // ---- owner state: tid<256 owns pair k=tid, all 8 batches ----
    float om0 = 0.f, om1 = 0.f, v0 = 0.f, v1 = 0.f;
    float xr0[NBATCH], xr1[NBATCH], zr0[NBATCH], zr1[NBATCH];
    if (tid < 256) {
        float2 o2 = sh.om[tid];            // own earlier write
        om0 = o2.x; om1 = o2.y;
        float2 vv = reinterpret_cast<const float2*>(z0b)[tid];
        v0 = vv.x * zinv; v1 = vv.y * zinv;
        #pragma unroll
        for (int b = 0; b < NBATCH; ++b) {
            float2 x2 = reinterpret_cast<const float2*>(x0)[b0 + b];
            xr0[b] = x2.x; xr1[b] = x2.y;
        }
        if (s == 0) {
            #pragma unroll
            for (int b = 0; b < NBATCH; ++b) {
                float2 z2 = reinterpret_cast<const float2*>(z0)
                                [(size_t)(b0 + b) * 256 + tid];
                zr0[b] = z2.x; zr1[b] = z2.y;
            }
        }
    }

    const int jg = tid >> 6;          // 16 j-groups of 32 rows
    const int cp = tid & 63;          // col-pair within slice
    const float2* A2 = reinterpret_cast<const float2*>(A);
    const size_t abase = (size_t)(64 * s) + cp;   // float2 col index

    for (int t = 0; t < NT; ++t) {
        // (1) owners: zx = T(omega@x) z0hat -> LDS
        if (tid < 256) {
            float e0[NBATCH], e1[NBATCH];
            #pragma unroll
            for (int b = 0; b < NBATCH; ++b) {
                float th = om0 * xr0[b] + om1 * xr1[b];
                float sn, cs;
                __sincosf(th, &sn, &cs);
                e0[b] = cs * v0 - sn * v1;
                e1[b] = sn * v0 + cs * v1;
            }
            sh.zxv[2 * tid][0]     = make_float4(e0[0], e0[1], e0[2], e0[3]);
            sh.zxv[2 * tid][1]     = make_float4(e0[4], e0[5], e0[6], e0[7]);
            sh.zxv[2 * tid + 1][0] = make_float4(e1[0], e1[1], e1[2], e1[3]);
            sh.zxv[2 * tid + 1][1] = make_float4(e1[4], e1[5], e1[6], e1[7]);
        }
        __syncthreads();   // B1

        // (2) matvec partials: cols {R0+2cp, R0+2cp+1} x rows 32jg..32jg+31
        {
            float a0[NBATCH] = {}, a1[NBATCH] = {};
            const int j0 = 32 * jg;
            #pragma unroll 4
            for (int jj = 0; jj < 32; ++jj) {
                float2 a = A2[(size_t)(j0 + jj) * 256 + abase];
                float4 zA = sh.zxv[j0 + jj][0];
                float4 zB = sh.zxv[j0 + jj][1];
                a0[0] = fmaf(a.x, zA.x, a0[0]);
                a0[1] = fmaf(a.x, zA.y, a0[1]);
                a0[2] = fmaf(a.x, zA.z, a0[2]);
                a0[3] = fmaf(a.x, zA.w, a0[3]);
                a0[4] = fmaf(a.x, zB.x, a0[4]);
                a0[5] = fmaf(a.x, zB.y, a0[5]);
                a0[6] = fmaf(a.x, zB.z, a0[6]);
                a0[7] = fmaf(a.x, zB.w, a0[7]);
                a1[0] = fmaf(a.y, zA.x, a1[0]);
                a1[1] = fmaf(a.y, zA.y, a1[1]);
                a1[2] = fmaf(a.y, zA.z, a1[2]);
                a1[3] = fmaf(a.y, zA.w, a1[3]);
                a1[4] = fmaf(a.y, zB.x, a1[4]);
                a1[5] = fmaf(a.y, zB.y, a1[5]);
                a1[6] = fmaf(a.y, zB.z, a1[6]);
                a1[7] = fmaf(a.y, zB.w, a1[7]);
            }
            float* pE = &sh.wpE[jg][cp][0];
            *reinterpret_cast<float4*>(pE)     = make_float4(a0[0], a0[1], a0[2], a0[3]);
            *reinterpret_cast<float4*>(pE + 4) = make_float4(a0[4], a0[5], a0[6], a0[7]);
            float* pO = &sh.wpO[jg][cp][0];
            *reinterpret_cast<float4*>(pO)     = make_float4(a1[0], a1[1], a1[2], a1[3]);
            *reinterpret_cast<float4*>(pO + 4) = make_float4(a1[4], a1[5], a1[6], a1[7]);
        }
        __syncthreads();   // B2

        // (3) reduce 16 jg + g_k: thread (kp=tid>>3, b=tid&7), tid<512
        if (tid < 512) {
            int kp = tid >> 3, b = tid & 7;
            float wE = 0.f, wO = 0.f;
            #pragma unroll
            for (int q = 0; q < 16; ++q) {
                wE += sh.wpE[q][kp][b];
                wO += sh.wpO[q][kp][b];
            }
            int kg = 64 * s + kp;      // global pair index
            const float* zxf = reinterpret_cast<const float*>(sh.zxv);
            float zc0 = zxf[(size_t)(2 * kg) * 8 + b];
            float zc1 = zxf[(size_t)(2 * kg + 1) * 8 + b];
            float gk = wO * zc0 - wE * zc1;
            float2 omk = sh.om[kg];
            float d0 = gk * omk.x, d1 = gk * omk.y;
            d0 += __shfl_xor(d0, 8, 64);
            d0 += __shfl_xor(d0, 16, 64);
            d0 += __shfl_xor(d0, 32, 64);
            d1 += __shfl_xor(d1, 8, 64);
            d1 += __shfl_xor(d1, 16, 64);
            d1 += __shfl_xor(d1, 32, 64);
            if ((tid & 63) < 8)
                sh.gpart[tid >> 6][tid & 7] = make_float2(d0, d1);
        }
        __syncthreads();   // B3

        // (4) fold 8 wave partials -> block partial dxpart[16]
        if (tid < 16) {
            int b = tid >> 1, c = tid & 1;
            float sum = 0.f;
            #pragma unroll
            for (int w = 0; w < 8; ++w)
                sum += c ? sh.gpart[w][b].y : sh.gpart[w][b].x;
            sh.dxpart[tid] = sum;
        }
        __syncthreads();   // B4

        // (5) wave 0: publish + all-gather the 4 slot partials
        if (tid < 64) {
            const unsigned int tag = (unsigned int)(t + 1);
            const int pq = t & 1;
            const int slotbase = (g * 2 + pq) * 4;
            if (tid < 16)
                __hip_atomic_store(&pay[(size_t)(slotbase + s) * 16 + tid],
                                   __float_as_uint(sh.dxpart[tid]),
                                   __ATOMIC_RELAXED, __HIP_MEMORY_SCOPE_AGENT);
            __threadfence();
            if (tid == 0)
                __hip_atomic_store(&flags[slotbase + s], tag,
                                   __ATOMIC_RELEASE, __HIP_MEMORY_SCOPE_AGENT);
            int ss = tid >> 4, j = tid & 15;
            unsigned int* f2 = &flags[slotbase + ss];
            int guard = 0;
            while (__hip_atomic_load(f2, __ATOMIC_ACQUIRE,
                                     __HIP_MEMORY_SCOPE_AGENT) != tag &&
                   ++guard < SPIN_CAP) {}
            float val = __uint_as_float(__hip_atomic_load(
                &pay[(size_t)(slotbase + ss) * 16 + j],
                __ATOMIC_RELAXED, __HIP_MEMORY_SCOPE_AGENT));
            val += __shfl_xor(val, 16, 64);
            val += __shfl_xor(val, 32, 64);
            if (tid < 16) sh.dxs[tid] = val;
        }
        __syncthreads();   // B5

        // (6) owners: dx_total, update x; s==0: rotate carry z + store
        if (tid < 256) {
            #pragma unroll
            for (int b = 0; b < NBATCH; ++b) {
                float2 pi = sh.dpi[b][t];
                float dt0 = pi.x + 0.1f * sh.dxs[2 * b];
                float dt1 = pi.y + 0.1f * sh.dxs[2 * b + 1];
                if (s == 0) {
                    float th = om0 * dt0 + om1 * dt1;
                    float sn, cs;
                    __sincosf(th, &sn, &cs);
                    float n0 = cs * zr0[b] - sn * zr1[b];
                    float n1 = sn * zr0[b] + cs * zr1[b];
                    zr0[b] = n0; zr1[b] = n1;
                    reinterpret_cast<float2*>(z_seq)
                        [((size_t)(b0 + b) * NT + t) * 256 + tid] =
                        make_float2(n0, n1);
                }
                xr0[b] = fminf(fmaxf(xr0[b] + dt0, 0.f), 2.0f);
                xr1[b] = fminf(fmaxf(xr1[b] + dt1, 0.f), 2.0f);
            }
            if (s == 0 && tid == 0) {
                #pragma unroll
                for (int b = 0; b < NBATCH; ++b)
                    reinterpret_cast<float2*>(x_seq)[(size_t)(b0 + b) * NT + t] =
                        make_float2(xr0[b], xr1[b]);
            }
        }
        // no barrier needed: dxs next written behind B1..B4 of t+1
    }
}

extern "C" void kernel_launch(void* const* d_in, const int* in_sizes, int n_in,
                              void* d_out, int out_size, void* d_ws, size_t ws_size,
                              hipStream_t stream) {
    (void)in_sizes; (void)n_in; (void)out_size; (void)ws_size;
    hipLaunchKernelGGL(can_main, dim3(NGROUP * 4), dim3(1024), 0, stream,
                       (const float*)d_in[0], (const float*)d_in[1],
                       (const float*)d_in[2], (const float*)d_in[3],
                       (const float*)d_in[4], (const float*)d_in[5],
                       (float*)d_out, (unsigned int*)d_ws);
}